// Round 4
// baseline (292.030 us; speedup 1.0000x reference)
//
#include <hip/hip_runtime.h>

#define NB 32      // batches
#define MM 448
#define CC 384
#define SS 512
#define KNN 8

// workspace byte offsets
#define WS_IDX   0u
#define WS_H1    524288u                 // int idx[32][512][8] before this
#define WS_PMAX  (WS_H1 + 4194304u)      // float h1[32][512][64]
#define WS_Q     (WS_PMAX + 262144u)     // float pmax[512][128] = 256 KB exact
#define WS_Y     (WS_Q + 49152u)         // float y[32][1024]
#define WS_G2    (WS_Y + 131072u)        // float g2[32][1024]
#define WS_BASEP (WS_G2 + 131072u)       // float basep[32][384]
#define WS_PP    WS_H1                   // pp[44][32][384] reuses h1 (dead after gc2)

__device__ __forceinline__ float wave_sum(float v) {
#pragma unroll
  for (int m = 1; m < 64; m <<= 1) v += __shfl_xor(v, m, 64);
  return v;
}

// ------------------------------------------------- K1: KNN + gc1, wave-per-point
__global__ __launch_bounds__(256) void k_knn_gc1(
    const float* __restrict__ skel,
    const float* __restrict__ w1root, const float* __restrict__ w1rel,
    const float* __restrict__ b1,
    int* __restrict__ idx_ws, float* __restrict__ h1_ws)
{
  int b   = blockIdx.x >> 7;          // 128 groups of 4 points per batch
  int grp = blockIdx.x & 127;
  __shared__ __align__(16) float4 sk[SS];
  const float* sb = skel + b * SS * 3;
  for (int t = threadIdx.x; t < SS; t += 256)
    sk[t] = make_float4(sb[t*3+0], sb[t*3+1], sb[t*3+2], 0.f);
  __syncthreads();

  int wave = threadIdx.x >> 6, lane = threadIdx.x & 63;
  int i = grp * 4 + wave;             // this wave's point
  float4 pi = sk[i];

  // lane owns candidates j = lane + 64*t
  float bd[KNN];
#pragma unroll
  for (int t = 0; t < KNN; t++) {
    int j = lane + (t << 6);
    float4 p = sk[j];
    float d2;
    {
      // match reference arithmetic exactly: (dx^2+dy^2)+dz^2, no fma contraction
#pragma clang fp contract(off)
      float dx = pi.x - p.x, dy = pi.y - p.y, dz = pi.z - p.z;
      d2 = (dx*dx + dy*dy) + dz*dz;
    }
    bd[t] = (j == i) ? 3e38f : d2;
  }

  // 8 rounds: global argmin (tie -> lower j, matching lax.top_k stability)
  int win[KNN];
  int* idx_base = idx_ws + (size_t)(b*SS + i) * KNN;
#pragma unroll
  for (int t = 0; t < KNN; t++) {
    float bestd = bd[0]; int bests = 0;
#pragma unroll
    for (int s = 1; s < KNN; s++)
      if (bd[s] < bestd) { bestd = bd[s]; bests = s; }
    int bestj = lane + (bests << 6);
#pragma unroll
    for (int m = 1; m < 64; m <<= 1) {
      float od = __shfl_xor(bestd, m, 64);
      int   oj = __shfl_xor(bestj, m, 64);
      if (od < bestd || (od == bestd && oj < bestj)) { bestd = od; bestj = oj; }
    }
    win[t] = bestj;                               // uniform across wave
    if (lane == t) idx_base[t] = bestj;
    if ((bestj & 63) == lane) {
      int sl = bestj >> 6;
#pragma unroll
      for (int s = 0; s < KNN; s++) if (s == sl) bd[s] = 3e38f;
    }
  }

  // neighbor coordinate sum in k-order (matches reference sum order)
  float a0 = 0.f, a1 = 0.f, a2 = 0.f;
#pragma unroll
  for (int t = 0; t < KNN; t++) {
    float4 n = sk[win[t]];
    a0 += n.x; a1 += n.y; a2 += n.z;
  }

  // gc1: 64 channels = 64 lanes, coalesced
  int c = lane;
  float h = b1[c] + pi.x*w1root[c] + pi.y*w1root[64+c] + pi.z*w1root[128+c]
                  + a0*w1rel[c]   + a1*w1rel[64+c]   + a2*w1rel[128+c];
  h = fmaxf(h, 0.f);
  h1_ws[(size_t)(b*SS + i) * 64 + lane] = h;
}

// -------- K2: gc2+max as one GEMM [16384x128]@[128x128], fused agg-gather + max
// block = 32 rows x 128 cols; thread = 4 rows x 4 cols; K in 4 LDS chunks of 32
__global__ __launch_bounds__(256) void k_gc2_max(
    const float* __restrict__ h1_ws, const int* __restrict__ idx_ws,
    const float* __restrict__ w2root, const float* __restrict__ w2rel,
    const float* __restrict__ b2, float* __restrict__ pmax)
{
  int b = blockIdx.x >> 4, chunk = blockIdx.x & 15;
  int r0 = chunk * 32;
  __shared__ __align__(16) float X[32*129];   // [row][k], stride 129 (broadcast-clean)
  __shared__ __align__(16) float Wt[32*128];  // k-chunk of stacked W
  __shared__ float mred[8*128];
  __shared__ int nbs[32*KNN];

  const float* h1b = h1_ws + (size_t)b * SS * 64;
  nbs[threadIdx.x] = idx_ws[(b*SS + r0)*KNN + threadIdx.x];   // 256 = 32*8
  // h-part of X: rows r0..r0+31, k 0..63 (coalesced 64-float rows)
#pragma unroll
  for (int p = 0; p < 8; p++) {
    int idx = threadIdx.x + 256*p;
    int r = idx >> 6, k = idx & 63;
    X[r*129 + k] = h1b[(r0 + r)*64 + k];
  }
  __syncthreads();   // nbs ready
  // agg-part: X[r][64+k] = sum over 8 neighbor rows (wave gathers whole rows, coalesced)
#pragma unroll
  for (int p = 0; p < 8; p++) {
    int idx = threadIdx.x + 256*p;
    int r = idx >> 6, k = idx & 63;
    const int* nb = nbs + r*KNN;
    float s = 0.f;
#pragma unroll
    for (int j = 0; j < KNN; j++) s += h1b[nb[j]*64 + k];
    X[r*129 + 64 + k] = s;
  }

  int rg = threadIdx.x >> 5, cg = threadIdx.x & 31;
  float acc[4][4];
#pragma unroll
  for (int r = 0; r < 4; r++)
#pragma unroll
    for (int u = 0; u < 4; u++) acc[r][u] = 0.f;

  const float* wsrc[4] = { w2root, w2root + 32*128, w2rel, w2rel + 32*128 };
#pragma unroll 1
  for (int ch = 0; ch < 4; ch++) {
    __syncthreads();   // X ready (ch=0) / prior chunk's reads done (ch>0)
    const float* ws = wsrc[ch];
#pragma unroll
    for (int p = 0; p < 16; p++) {
      int idx = threadIdx.x + 256*p;
      Wt[idx] = ws[idx];                 // coalesced
    }
    __syncthreads();
    int kb = ch * 32;
    const float* xr0 = X + (rg*4+0)*129 + kb;
    const float* xr1 = X + (rg*4+1)*129 + kb;
    const float* xr2 = X + (rg*4+2)*129 + kb;
    const float* xr3 = X + (rg*4+3)*129 + kb;
#pragma unroll 4
    for (int k = 0; k < 32; k++) {
      float4 w4 = *(const float4*)(Wt + k*128 + cg*4);
      float x0 = xr0[k], x1 = xr1[k], x2 = xr2[k], x3 = xr3[k];
      acc[0][0] += x0*w4.x; acc[0][1] += x0*w4.y; acc[0][2] += x0*w4.z; acc[0][3] += x0*w4.w;
      acc[1][0] += x1*w4.x; acc[1][1] += x1*w4.y; acc[1][2] += x1*w4.z; acc[1][3] += x1*w4.w;
      acc[2][0] += x2*w4.x; acc[2][1] += x2*w4.y; acc[2][2] += x2*w4.z; acc[2][3] += x2*w4.w;
      acc[3][0] += x3*w4.x; acc[3][1] += x3*w4.y; acc[3][2] += x3*w4.z; acc[3][3] += x3*w4.w;
    }
  }
  // epilogue: max over this block's 32 rows, bias added after (commutes with max)
#pragma unroll
  for (int u = 0; u < 4; u++)
    mred[rg*128 + cg*4 + u] =
      fmaxf(fmaxf(acc[0][u], acc[1][u]), fmaxf(acc[2][u], acc[3][u]));
  __syncthreads();
  if (threadIdx.x < 128) {
    int col = threadIdx.x;
    float mx = mred[col];
#pragma unroll
    for (int g = 1; g < 8; g++) mx = fmaxf(mx, mred[g*128 + col]);
    pmax[(size_t)(b*16 + chunk)*128 + col] = mx + b2[col];
  }
}

// ---------- K3: fused proxy-max -> kv -> v -> q chain (one block per batch)
__global__ __launch_bounds__(384) void k_attn_chain(
    const float* __restrict__ pmax,
    const float* __restrict__ proj_w, const float* __restrict__ proj_b,
    const float* __restrict__ attn_in_w, const float* __restrict__ attn_in_b,
    const float* __restrict__ attn_out_w, const float* __restrict__ attn_out_b,
    float* __restrict__ q_ws)
{
  int b = blockIdx.x, t = threadIdx.x;
  __shared__ float proxy[128];
  __shared__ float kv[CC];
  __shared__ float vv[CC];
  if (t < 128) {
    float m = -3e38f;
    for (int ch = 0; ch < 16; ch++) m = fmaxf(m, pmax[(size_t)(b*16 + ch)*128 + t]);
    proxy[t] = m;
  }
  __syncthreads();
  {  // kv = proxy @ proj_w + proj_b   (proj_w [128][384], t-coalesced)
    float acc = proj_b[t];
    for (int s = 0; s < 128; s++) acc += proxy[s] * proj_w[s*CC + t];
    kv[t] = acc;
  }
  __syncthreads();
  int wv = t >> 6, lane = t & 63;
  {  // vv = kv @ wv.T + bv  : wave-per-output, 64 outputs per wave
    float x0 = kv[lane*6+0], x1 = kv[lane*6+1], x2 = kv[lane*6+2];
    float x3 = kv[lane*6+3], x4 = kv[lane*6+4], x5 = kv[lane*6+5];
#pragma unroll 8
    for (int u = 0; u < 64; u++) {
      int o = wv*64 + u;
      const float* wr = attn_in_w + (size_t)(2*CC + o) * CC + lane*6;
      float2 wa = *(const float2*)wr;
      float2 wb = *(const float2*)(wr + 2);
      float2 wc = *(const float2*)(wr + 4);
      float p = wa.x*x0 + wa.y*x1 + wb.x*x2 + wb.y*x3 + wc.x*x4 + wc.y*x5;
      p = wave_sum(p);
      if (lane == 0) vv[o] = attn_in_b[2*CC + o] + p;
    }
  }
  __syncthreads();
  {  // q = vv @ attn_out_w.T + b
    float x0 = vv[lane*6+0], x1 = vv[lane*6+1], x2 = vv[lane*6+2];
    float x3 = vv[lane*6+3], x4 = vv[lane*6+4], x5 = vv[lane*6+5];
#pragma unroll 8
    for (int u = 0; u < 64; u++) {
      int o = wv*64 + u;
      const float* wr = attn_out_w + (size_t)o * CC + lane*6;
      float2 wa = *(const float2*)wr;
      float2 wb = *(const float2*)(wr + 2);
      float2 wc = *(const float2*)(wr + 4);
      float p = wa.x*x0 + wa.y*x1 + wb.x*x2 + wb.y*x3 + wc.x*x4 + wc.y*x5;
      p = wave_sum(p);
      if (lane == 0) q_ws[b*CC + o] = attn_out_b[o] + p;
    }
  }
}

// ------------------------------- K4: inc1 + BN + leaky, wave-per-output coalesced
__global__ __launch_bounds__(256) void k_inc1_bn(
    const float* __restrict__ q_ws, const float* __restrict__ inc1_w,
    const float* __restrict__ inc1_b,
    const float* __restrict__ bng, const float* __restrict__ bnb,
    const float* __restrict__ bnm, const float* __restrict__ bnv,
    float* __restrict__ y_ws)
{
  int b = blockIdx.x >> 5, og = blockIdx.x & 31;
  int wv = threadIdx.x >> 6, lane = threadIdx.x & 63;
  __shared__ float xs[CC];
  for (int t = threadIdx.x; t < CC; t += 256) xs[t] = q_ws[b*CC + t];
  __syncthreads();
  float x0 = xs[lane*6+0], x1 = xs[lane*6+1], x2 = xs[lane*6+2];
  float x3 = xs[lane*6+3], x4 = xs[lane*6+4], x5 = xs[lane*6+5];
#pragma unroll
  for (int u = 0; u < 8; u++) {
    int o = og*32 + wv*8 + u;
    const float* wr = inc1_w + (size_t)o * CC + lane*6;
    float2 wa = *(const float2*)wr;
    float2 wb = *(const float2*)(wr + 2);
    float2 wc = *(const float2*)(wr + 4);
    float p = wa.x*x0 + wa.y*x1 + wb.x*x2 + wb.y*x3 + wc.x*x4 + wc.y*x5;
    p = wave_sum(p);
    if (lane == 0) {
      float acc = p + inc1_b[o];
      float z = bng[o] * (acc - bnm[o]) * rsqrtf(bnv[o] + 1e-5f) + bnb[o];
      y_ws[b*1024 + o] = (z >= 0.f) ? z : 0.2f * z;
    }
  }
}

// ----------------------------------------- K5: inc2, wave-per-output coalesced
__global__ __launch_bounds__(256) void k_inc2(
    const float* __restrict__ y_ws, const float* __restrict__ inc2_w,
    const float* __restrict__ inc2_b, float* __restrict__ g2_ws)
{
  int b = blockIdx.x >> 5, og = blockIdx.x & 31;
  int wv = threadIdx.x >> 6, lane = threadIdx.x & 63;
  __shared__ __align__(16) float xs[1024];
  for (int t = threadIdx.x; t < 1024; t += 256) xs[t] = y_ws[b*1024 + t];
  __syncthreads();
  float4 X0 = *(const float4*)(xs + lane*16 + 0);
  float4 X1 = *(const float4*)(xs + lane*16 + 4);
  float4 X2 = *(const float4*)(xs + lane*16 + 8);
  float4 X3 = *(const float4*)(xs + lane*16 + 12);
#pragma unroll
  for (int u = 0; u < 8; u++) {
    int o = og*32 + wv*8 + u;
    const float* wr = inc2_w + (size_t)o * 1024 + lane*16;
    float4 W0 = *(const float4*)(wr + 0);
    float4 W1 = *(const float4*)(wr + 4);
    float4 W2 = *(const float4*)(wr + 8);
    float4 W3 = *(const float4*)(wr + 12);
    float p = W0.x*X0.x + W0.y*X0.y + W0.z*X0.z + W0.w*X0.w
            + W1.x*X1.x + W1.y*X1.y + W1.z*X1.z + W1.w*X1.w
            + W2.x*X2.x + W2.y*X2.y + W2.z*X2.z + W2.w*X2.w
            + W3.x*X3.x + W3.y*X3.y + W3.z*X3.z + W3.w*X3.w;
    p = wave_sum(p);
    if (lane == 0) g2_ws[b*1024 + o] = p + inc2_b[o];
  }
}

// ------------- K6a: base partial GEMM: pp[cg][b][o] = x[b][c0:c0+32] @ W[c0:c0+32]
__global__ __launch_bounds__(256) void k_basep(
    const float* __restrict__ g2_ws, const float* __restrict__ q_ws,
    const float* __restrict__ red_w, float* __restrict__ pp)
{
  int cg = blockIdx.x;          // 0..43 (c0 = cg*32; <1024 -> g2, else q)
  int o0 = blockIdx.y * 64;     // 0..5
  int c0 = cg * 32;
  __shared__ __align__(16) float xs[32*33];   // [c][b] padded
  __shared__ __align__(16) float wt[32*64];   // [c][o]
#pragma unroll
  for (int p = 0; p < 8; p++) {
    int idx = threadIdx.x + 256*p;
    int c = idx >> 6, o = idx & 63;
    wt[idx] = red_w[(size_t)(c0 + c)*CC + o0 + o];   // wave = 256B contiguous
  }
  {
    int b = threadIdx.x >> 3, cp = threadIdx.x & 7;
    const float* src = (cg < 32) ? (g2_ws + b*1024 + c0)
                                 : (q_ws  + b*CC   + (c0 - 1024));
    float4 v = *(const float4*)(src + cp*4);
    xs[(cp*4+0)*33 + b] = v.x;
    xs[(cp*4+1)*33 + b] = v.y;
    xs[(cp*4+2)*33 + b] = v.z;
    xs[(cp*4+3)*33 + b] = v.w;
  }
  __syncthreads();
  int b = threadIdx.x >> 3, og = threadIdx.x & 7;
  float acc[8];
#pragma unroll
  for (int u = 0; u < 8; u++) acc[u] = 0.f;
#pragma unroll 8
  for (int c = 0; c < 32; c++) {
    float xv = xs[c*33 + b];
    float4 w0 = *(const float4*)(wt + c*64 + og*8);
    float4 w1 = *(const float4*)(wt + c*64 + og*8 + 4);
    acc[0] += xv*w0.x; acc[1] += xv*w0.y; acc[2] += xv*w0.z; acc[3] += xv*w0.w;
    acc[4] += xv*w1.x; acc[5] += xv*w1.y; acc[6] += xv*w1.z; acc[7] += xv*w1.w;
  }
  float* dst = pp + (size_t)(cg*32 + b)*CC + o0 + og*8;
  *(float4*)dst       = make_float4(acc[0], acc[1], acc[2], acc[3]);
  *(float4*)(dst + 4) = make_float4(acc[4], acc[5], acc[6], acc[7]);
}

// ------------------------------------ K6b: reduce 44 partials -> basep[32][384]
__global__ __launch_bounds__(256) void k_base_red(
    const float* __restrict__ pp, float* __restrict__ basep)
{
  int idx = blockIdx.x * 256 + threadIdx.x;   // < 12288
  float s = 0.f;
#pragma unroll 4
  for (int cg = 0; cg < 44; cg++) s += pp[cg*12288 + idx];
  basep[idx] = s;
}

// --------------------------------------------- K7: out = base + coarse @ red_w3
__global__ __launch_bounds__(256) void k_out(
    const float* __restrict__ basep, const float* __restrict__ red_b,
    const float* __restrict__ red_w, const float* __restrict__ coarse,
    float* __restrict__ out)
{
  int gid = blockIdx.x * 256 + threadIdx.x;   // < 32*448*96 exactly
  int c4 = gid % 96;
  int row = gid / 96;                          // b*448 + m
  int b = row / 448;
  int c = c4 * 4;
  float4 p0 = *(const float4*)(basep + b*CC + c);
  float4 rb = *(const float4*)(red_b + c);
  const float* cr = coarse + (size_t)row * 3;
  float cx = cr[0], cy = cr[1], cz = cr[2];
  float4 w0 = *(const float4*)(red_w + (size_t)1408*CC + c);
  float4 w1 = *(const float4*)(red_w + (size_t)1409*CC + c);
  float4 w2 = *(const float4*)(red_w + (size_t)1410*CC + c);
  float4 o4;
  o4.x = p0.x + rb.x + cx*w0.x + cy*w1.x + cz*w2.x;
  o4.y = p0.y + rb.y + cx*w0.y + cy*w1.y + cz*w2.y;
  o4.z = p0.z + rb.z + cx*w0.z + cy*w1.z + cz*w2.z;
  o4.w = p0.w + rb.w + cx*w0.w + cy*w1.w + cz*w2.w;
  *(float4*)(out + (size_t)row*CC + c) = o4;
}

extern "C" void kernel_launch(void* const* d_in, const int* in_sizes, int n_in,
                              void* d_out, int out_size, void* d_ws, size_t ws_size,
                              hipStream_t stream)
{
  (void)in_sizes; (void)n_in; (void)out_size; (void)ws_size;
  // d_in[0] is q (B,M,C): provably unused — attention softmax is uniform.
  const float* coarse = (const float*)d_in[1];
  const float* skel   = (const float*)d_in[2];
  const float* g1wr   = (const float*)d_in[3];
  const float* g1wl   = (const float*)d_in[4];
  const float* g1b    = (const float*)d_in[5];
  const float* g2wr   = (const float*)d_in[6];
  const float* g2wl   = (const float*)d_in[7];
  const float* g2b    = (const float*)d_in[8];
  const float* projw  = (const float*)d_in[9];
  const float* projb  = (const float*)d_in[10];
  const float* aiw    = (const float*)d_in[11];
  const float* aib    = (const float*)d_in[12];
  const float* aow    = (const float*)d_in[13];
  const float* aob    = (const float*)d_in[14];
  const float* i1w    = (const float*)d_in[15];
  const float* i1b    = (const float*)d_in[16];
  const float* bng    = (const float*)d_in[17];
  const float* bnb    = (const float*)d_in[18];
  const float* bnm    = (const float*)d_in[19];
  const float* bnv    = (const float*)d_in[20];
  const float* i2w    = (const float*)d_in[21];
  const float* i2b    = (const float*)d_in[22];
  const float* redw   = (const float*)d_in[23];
  const float* redb   = (const float*)d_in[24];
  float* out = (float*)d_out;

  char* ws = (char*)d_ws;
  int*   idx_ws = (int*)(ws + WS_IDX);
  float* h1_ws  = (float*)(ws + WS_H1);
  float* pmax   = (float*)(ws + WS_PMAX);
  float* q_ws   = (float*)(ws + WS_Q);
  float* y_ws   = (float*)(ws + WS_Y);
  float* g2_ws  = (float*)(ws + WS_G2);
  float* basep  = (float*)(ws + WS_BASEP);
  float* pp     = (float*)(ws + WS_PP);   // reuses h1 region (dead after gc2)

  k_knn_gc1<<<4096, 256, 0, stream>>>(skel, g1wr, g1wl, g1b, idx_ws, h1_ws);
  k_gc2_max<<<512, 256, 0, stream>>>(h1_ws, idx_ws, g2wr, g2wl, g2b, pmax);
  k_attn_chain<<<32, 384, 0, stream>>>(pmax, projw, projb, aiw, aib, aow, aob, q_ws);
  k_inc1_bn<<<1024, 256, 0, stream>>>(q_ws, i1w, i1b, bng, bnb, bnm, bnv, y_ws);
  k_inc2<<<1024, 256, 0, stream>>>(y_ws, i2w, i2b, g2_ws);
  k_basep<<<dim3(44, 6), 256, 0, stream>>>(g2_ws, q_ws, redw, pp);
  k_base_red<<<48, 256, 0, stream>>>(pp, basep);
  k_out<<<5376, 256, 0, stream>>>(basep, redb, redw, coarse, out);
}

// Round 5
// 234.175 us; speedup vs baseline: 1.2471x; 1.2471x over previous
//
#include <hip/hip_runtime.h>

#define NB 32      // batches
#define MM 448
#define CC 384
#define SS 512
#define KNN 8

// workspace byte offsets
#define WS_IDX   0u
#define WS_H1    524288u                 // int idx[32][512][8] before this
#define WS_PMAX  (WS_H1 + 4194304u)      // float h1[32][512][64]
#define WS_Q     (WS_PMAX + 262144u)     // float pmax[512][128] = 256 KB exact
#define WS_Y     (WS_Q + 49152u)         // float y[32][1024]
#define WS_G2    (WS_Y + 131072u)        // float g2[32][1024]
#define WS_BASEP (WS_G2 + 131072u)       // float basep[32][384]
#define WS_PP    WS_H1                   // pp[44][32][384] reuses h1 (dead after gc2)
// kv/vv reuse idx region (idx dead after gc2; chain runs after gc2)
#define WS_KV    WS_IDX
#define WS_VV    (WS_IDX + 49152u)

__device__ __forceinline__ float wave_sum(float v) {
#pragma unroll
  for (int m = 1; m < 64; m <<= 1) v += __shfl_xor(v, m, 64);
  return v;
}

// ------------------------------------------------- K1: KNN + gc1, wave-per-point
__global__ __launch_bounds__(256) void k_knn_gc1(
    const float* __restrict__ skel,
    const float* __restrict__ w1root, const float* __restrict__ w1rel,
    const float* __restrict__ b1,
    int* __restrict__ idx_ws, float* __restrict__ h1_ws)
{
  int b   = blockIdx.x >> 7;          // 128 groups of 4 points per batch
  int grp = blockIdx.x & 127;
  __shared__ __align__(16) float4 sk[SS];
  const float* sb = skel + b * SS * 3;
  for (int t = threadIdx.x; t < SS; t += 256)
    sk[t] = make_float4(sb[t*3+0], sb[t*3+1], sb[t*3+2], 0.f);
  __syncthreads();

  int wave = threadIdx.x >> 6, lane = threadIdx.x & 63;
  int i = grp * 4 + wave;             // this wave's point
  float4 pi = sk[i];

  // lane owns candidates j = lane + 64*t
  float bd[KNN];
#pragma unroll
  for (int t = 0; t < KNN; t++) {
    int j = lane + (t << 6);
    float4 p = sk[j];
    float d2;
    {
      // match reference arithmetic exactly: (dx^2+dy^2)+dz^2, no fma contraction
#pragma clang fp contract(off)
      float dx = pi.x - p.x, dy = pi.y - p.y, dz = pi.z - p.z;
      d2 = (dx*dx + dy*dy) + dz*dz;
    }
    bd[t] = (j == i) ? 3e38f : d2;
  }

  // 8 rounds: global argmin (tie -> lower j, matching lax.top_k stability)
  int win[KNN];
  int* idx_base = idx_ws + (size_t)(b*SS + i) * KNN;
#pragma unroll
  for (int t = 0; t < KNN; t++) {
    float bestd = bd[0]; int bests = 0;
#pragma unroll
    for (int s = 1; s < KNN; s++)
      if (bd[s] < bestd) { bestd = bd[s]; bests = s; }
    int bestj = lane + (bests << 6);
#pragma unroll
    for (int m = 1; m < 64; m <<= 1) {
      float od = __shfl_xor(bestd, m, 64);
      int   oj = __shfl_xor(bestj, m, 64);
      if (od < bestd || (od == bestd && oj < bestj)) { bestd = od; bestj = oj; }
    }
    win[t] = bestj;                               // uniform across wave
    if (lane == t) idx_base[t] = bestj;
    if ((bestj & 63) == lane) {
      int sl = bestj >> 6;
#pragma unroll
      for (int s = 0; s < KNN; s++) if (s == sl) bd[s] = 3e38f;
    }
  }

  // neighbor coordinate sum in k-order (matches reference sum order)
  float a0 = 0.f, a1 = 0.f, a2 = 0.f;
#pragma unroll
  for (int t = 0; t < KNN; t++) {
    float4 n = sk[win[t]];
    a0 += n.x; a1 += n.y; a2 += n.z;
  }

  // gc1: 64 channels = 64 lanes, coalesced
  int c = lane;
  float h = b1[c] + pi.x*w1root[c] + pi.y*w1root[64+c] + pi.z*w1root[128+c]
                  + a0*w1rel[c]   + a1*w1rel[64+c]   + a2*w1rel[128+c];
  h = fmaxf(h, 0.f);
  h1_ws[(size_t)(b*SS + i) * 64 + lane] = h;
}

// -------- K2: gc2+max as one GEMM [16384x128]@[128x128], fused agg-gather + max
__global__ __launch_bounds__(256) void k_gc2_max(
    const float* __restrict__ h1_ws, const int* __restrict__ idx_ws,
    const float* __restrict__ w2root, const float* __restrict__ w2rel,
    const float* __restrict__ b2, float* __restrict__ pmax)
{
  int b = blockIdx.x >> 4, chunk = blockIdx.x & 15;
  int r0 = chunk * 32;
  __shared__ __align__(16) float X[32*129];   // [row][k], stride 129
  __shared__ __align__(16) float Wt[32*128];  // k-chunk of stacked W
  __shared__ float mred[8*128];
  __shared__ int nbs[32*KNN];

  const float* h1b = h1_ws + (size_t)b * SS * 64;
  nbs[threadIdx.x] = idx_ws[(b*SS + r0)*KNN + threadIdx.x];   // 256 = 32*8
#pragma unroll
  for (int p = 0; p < 8; p++) {
    int idx = threadIdx.x + 256*p;
    int r = idx >> 6, k = idx & 63;
    X[r*129 + k] = h1b[(r0 + r)*64 + k];
  }
  __syncthreads();   // nbs ready
#pragma unroll
  for (int p = 0; p < 8; p++) {
    int idx = threadIdx.x + 256*p;
    int r = idx >> 6, k = idx & 63;
    const int* nb = nbs + r*KNN;
    float s = 0.f;
#pragma unroll
    for (int j = 0; j < KNN; j++) s += h1b[nb[j]*64 + k];
    X[r*129 + 64 + k] = s;
  }

  int rg = threadIdx.x >> 5, cg = threadIdx.x & 31;
  float acc[4][4];
#pragma unroll
  for (int r = 0; r < 4; r++)
#pragma unroll
    for (int u = 0; u < 4; u++) acc[r][u] = 0.f;

  const float* wsrc[4] = { w2root, w2root + 32*128, w2rel, w2rel + 32*128 };
#pragma unroll 1
  for (int ch = 0; ch < 4; ch++) {
    __syncthreads();
    const float* ws = wsrc[ch];
#pragma unroll
    for (int p = 0; p < 16; p++) {
      int idx = threadIdx.x + 256*p;
      Wt[idx] = ws[idx];                 // coalesced
    }
    __syncthreads();
    int kb = ch * 32;
    const float* xr0 = X + (rg*4+0)*129 + kb;
    const float* xr1 = X + (rg*4+1)*129 + kb;
    const float* xr2 = X + (rg*4+2)*129 + kb;
    const float* xr3 = X + (rg*4+3)*129 + kb;
#pragma unroll 4
    for (int k = 0; k < 32; k++) {
      float4 w4 = *(const float4*)(Wt + k*128 + cg*4);
      float x0 = xr0[k], x1 = xr1[k], x2 = xr2[k], x3 = xr3[k];
      acc[0][0] += x0*w4.x; acc[0][1] += x0*w4.y; acc[0][2] += x0*w4.z; acc[0][3] += x0*w4.w;
      acc[1][0] += x1*w4.x; acc[1][1] += x1*w4.y; acc[1][2] += x1*w4.z; acc[1][3] += x1*w4.w;
      acc[2][0] += x2*w4.x; acc[2][1] += x2*w4.y; acc[2][2] += x2*w4.z; acc[2][3] += x2*w4.w;
      acc[3][0] += x3*w4.x; acc[3][1] += x3*w4.y; acc[3][2] += x3*w4.z; acc[3][3] += x3*w4.w;
    }
  }
#pragma unroll
  for (int u = 0; u < 4; u++)
    mred[rg*128 + cg*4 + u] =
      fmaxf(fmaxf(acc[0][u], acc[1][u]), fmaxf(acc[2][u], acc[3][u]));
  __syncthreads();
  if (threadIdx.x < 128) {
    int col = threadIdx.x;
    float mx = mred[col];
#pragma unroll
    for (int g = 1; g < 8; g++) mx = fmaxf(mx, mred[g*128 + col]);
    pmax[(size_t)(b*16 + chunk)*128 + col] = mx + b2[col];
  }
}

// ------------------------------------------------- K3a: proxy max + kv (coalesced)
__global__ __launch_bounds__(384) void k_proxy_kv(
    const float* __restrict__ pmax,
    const float* __restrict__ proj_w, const float* __restrict__ proj_b,
    float* __restrict__ kv_ws)
{
  int b = blockIdx.x, t = threadIdx.x;
  __shared__ float proxy[128];
  if (t < 128) {
    float m = -3e38f;
    for (int ch = 0; ch < 16; ch++) m = fmaxf(m, pmax[(size_t)(b*16 + ch)*128 + t]);
    proxy[t] = m;
  }
  __syncthreads();
  float acc = proj_b[t];
  for (int s = 0; s < 128; s++) acc += proxy[s] * proj_w[s*CC + t];   // coalesced
  kv_ws[b*CC + t] = acc;
}

// ------------------------- K3b/K3c: generic 384->384 matvec, wave-per-output dot
__global__ __launch_bounds__(256) void k_mv384(
    const float* __restrict__ xin, const float* __restrict__ w, int row0,
    const float* __restrict__ bias, int bias0, float* __restrict__ out)
{
  int b = blockIdx.x, og = blockIdx.y;
  int wv = threadIdx.x >> 6, lane = threadIdx.x & 63;
  __shared__ float xs[CC];
  for (int t = threadIdx.x; t < CC; t += 256) xs[t] = xin[b*CC + t];
  __syncthreads();
  float x0 = xs[lane*6+0], x1 = xs[lane*6+1], x2 = xs[lane*6+2];
  float x3 = xs[lane*6+3], x4 = xs[lane*6+4], x5 = xs[lane*6+5];
#pragma unroll
  for (int u = 0; u < 8; u++) {
    int o = og*32 + wv*8 + u;
    const float* wr = w + (size_t)(row0 + o) * CC + lane*6;
    float2 wa = *(const float2*)wr;
    float2 wb = *(const float2*)(wr + 2);
    float2 wc = *(const float2*)(wr + 4);
    float p = wa.x*x0 + wa.y*x1 + wb.x*x2 + wb.y*x3 + wc.x*x4 + wc.y*x5;
    p = wave_sum(p);
    if (lane == 0) out[b*CC + o] = bias[bias0 + o] + p;
  }
}

// ---------- K4: inc1 + BN + leaky. 4 lanes per output, contiguous quarter-rows.
__global__ __launch_bounds__(256) void k_inc1_bn(
    const float* __restrict__ q_ws, const float* __restrict__ inc1_w,
    const float* __restrict__ inc1_b,
    const float* __restrict__ bng, const float* __restrict__ bnb,
    const float* __restrict__ bnm, const float* __restrict__ bnv,
    float* __restrict__ y_ws)
{
  int b = blockIdx.x >> 4, og = blockIdx.x & 15;
  int t = threadIdx.x;
  int o = og*64 + (t >> 2), qq = t & 3;
  __shared__ __align__(16) float xs[CC];
  for (int i = t; i < CC; i += 256) xs[i] = q_ws[b*CC + i];
  __syncthreads();
  const float* wr = inc1_w + (size_t)o * CC + qq*96;
  const float* xr = xs + qq*96;
  float acc = 0.f;
#pragma unroll
  for (int kk = 0; kk < 96; kk += 4) {
    float4 w4 = *(const float4*)(wr + kk);
    float4 x4 = *(const float4*)(xr + kk);
    acc += w4.x*x4.x + w4.y*x4.y + w4.z*x4.z + w4.w*x4.w;
  }
  acc += __shfl_xor(acc, 1, 64);
  acc += __shfl_xor(acc, 2, 64);
  if (qq == 0) {
    float a = acc + inc1_b[o];
    float z = bng[o] * (a - bnm[o]) * rsqrtf(bnv[o] + 1e-5f) + bnb[o];
    y_ws[b*1024 + o] = (z >= 0.f) ? z : 0.2f * z;
  }
}

// ---------------- K5: inc2. 4 lanes per output, contiguous quarter-rows (K=1024).
__global__ __launch_bounds__(256) void k_inc2(
    const float* __restrict__ y_ws, const float* __restrict__ inc2_w,
    const float* __restrict__ inc2_b, float* __restrict__ g2_ws)
{
  int b = blockIdx.x >> 4, og = blockIdx.x & 15;
  int t = threadIdx.x;
  int o = og*64 + (t >> 2), qq = t & 3;
  __shared__ __align__(16) float xs[1024];
  for (int i = t; i < 1024; i += 256) xs[i] = y_ws[b*1024 + i];
  __syncthreads();
  const float* wr = inc2_w + (size_t)o * 1024 + qq*256;
  const float* xr = xs + qq*256;
  float acc = 0.f;
#pragma unroll 8
  for (int kk = 0; kk < 256; kk += 4) {
    float4 w4 = *(const float4*)(wr + kk);
    float4 x4 = *(const float4*)(xr + kk);
    acc += w4.x*x4.x + w4.y*x4.y + w4.z*x4.z + w4.w*x4.w;
  }
  acc += __shfl_xor(acc, 1, 64);
  acc += __shfl_xor(acc, 2, 64);
  if (qq == 0) g2_ws[b*1024 + o] = acc + inc2_b[o];
}

// ------------- K6a: base partial GEMM: pp[cg][b][o] = x[b][c0:c0+32] @ W[c0:c0+32]
__global__ __launch_bounds__(256) void k_basep(
    const float* __restrict__ g2_ws, const float* __restrict__ q_ws,
    const float* __restrict__ red_w, float* __restrict__ pp)
{
  int cg = blockIdx.x;          // 0..43 (c0 = cg*32; <1024 -> g2, else q)
  int o0 = blockIdx.y * 64;     // 0..5
  int c0 = cg * 32;
  __shared__ __align__(16) float xs[32*33];   // [c][b] padded
  __shared__ __align__(16) float wt[32*64];   // [c][o]
#pragma unroll
  for (int p = 0; p < 8; p++) {
    int idx = threadIdx.x + 256*p;
    int c = idx >> 6, o = idx & 63;
    wt[idx] = red_w[(size_t)(c0 + c)*CC + o0 + o];
  }
  {
    int b = threadIdx.x >> 3, cp = threadIdx.x & 7;
    const float* src = (cg < 32) ? (g2_ws + b*1024 + c0)
                                 : (q_ws  + b*CC   + (c0 - 1024));
    float4 v = *(const float4*)(src + cp*4);
    xs[(cp*4+0)*33 + b] = v.x;
    xs[(cp*4+1)*33 + b] = v.y;
    xs[(cp*4+2)*33 + b] = v.z;
    xs[(cp*4+3)*33 + b] = v.w;
  }
  __syncthreads();
  int b = threadIdx.x >> 3, og = threadIdx.x & 7;
  float acc[8];
#pragma unroll
  for (int u = 0; u < 8; u++) acc[u] = 0.f;
#pragma unroll 8
  for (int c = 0; c < 32; c++) {
    float xv = xs[c*33 + b];
    float4 w0 = *(const float4*)(wt + c*64 + og*8);
    float4 w1 = *(const float4*)(wt + c*64 + og*8 + 4);
    acc[0] += xv*w0.x; acc[1] += xv*w0.y; acc[2] += xv*w0.z; acc[3] += xv*w0.w;
    acc[4] += xv*w1.x; acc[5] += xv*w1.y; acc[6] += xv*w1.z; acc[7] += xv*w1.w;
  }
  float* dst = pp + (size_t)(cg*32 + b)*CC + o0 + og*8;
  *(float4*)dst       = make_float4(acc[0], acc[1], acc[2], acc[3]);
  *(float4*)(dst + 4) = make_float4(acc[4], acc[5], acc[6], acc[7]);
}

// ------------------------------------ K6b: reduce 44 partials -> basep[32][384]
__global__ __launch_bounds__(256) void k_base_red(
    const float* __restrict__ pp, float* __restrict__ basep)
{
  int idx = blockIdx.x * 256 + threadIdx.x;   // < 12288
  float s = 0.f;
#pragma unroll 4
  for (int cg = 0; cg < 44; cg++) s += pp[cg*12288 + idx];
  basep[idx] = s;
}

// --------------------------------------------- K7: out = base + coarse @ red_w3
__global__ __launch_bounds__(256) void k_out(
    const float* __restrict__ basep, const float* __restrict__ red_b,
    const float* __restrict__ red_w, const float* __restrict__ coarse,
    float* __restrict__ out)
{
  int gid = blockIdx.x * 256 + threadIdx.x;   // < 32*448*96 exactly
  int c4 = gid % 96;
  int row = gid / 96;                          // b*448 + m
  int b = row / 448;
  int c = c4 * 4;
  float4 p0 = *(const float4*)(basep + b*CC + c);
  float4 rb = *(const float4*)(red_b + c);
  const float* cr = coarse + (size_t)row * 3;
  float cx = cr[0], cy = cr[1], cz = cr[2];
  float4 w0 = *(const float4*)(red_w + (size_t)1408*CC + c);
  float4 w1 = *(const float4*)(red_w + (size_t)1409*CC + c);
  float4 w2 = *(const float4*)(red_w + (size_t)1410*CC + c);
  float4 o4;
  o4.x = p0.x + rb.x + cx*w0.x + cy*w1.x + cz*w2.x;
  o4.y = p0.y + rb.y + cx*w0.y + cy*w1.y + cz*w2.y;
  o4.z = p0.z + rb.z + cx*w0.z + cy*w1.z + cz*w2.z;
  o4.w = p0.w + rb.w + cx*w0.w + cy*w1.w + cz*w2.w;
  *(float4*)(out + (size_t)row*CC + c) = o4;
}

extern "C" void kernel_launch(void* const* d_in, const int* in_sizes, int n_in,
                              void* d_out, int out_size, void* d_ws, size_t ws_size,
                              hipStream_t stream)
{
  (void)in_sizes; (void)n_in; (void)out_size; (void)ws_size;
  // d_in[0] is q (B,M,C): provably unused — attention softmax is uniform.
  const float* coarse = (const float*)d_in[1];
  const float* skel   = (const float*)d_in[2];
  const float* g1wr   = (const float*)d_in[3];
  const float* g1wl   = (const float*)d_in[4];
  const float* g1b    = (const float*)d_in[5];
  const float* g2wr   = (const float*)d_in[6];
  const float* g2wl   = (const float*)d_in[7];
  const float* g2b    = (const float*)d_in[8];
  const float* projw  = (const float*)d_in[9];
  const float* projb  = (const float*)d_in[10];
  const float* aiw    = (const float*)d_in[11];
  const float* aib    = (const float*)d_in[12];
  const float* aow    = (const float*)d_in[13];
  const float* aob    = (const float*)d_in[14];
  const float* i1w    = (const float*)d_in[15];
  const float* i1b    = (const float*)d_in[16];
  const float* bng    = (const float*)d_in[17];
  const float* bnb    = (const float*)d_in[18];
  const float* bnm    = (const float*)d_in[19];
  const float* bnv    = (const float*)d_in[20];
  const float* i2w    = (const float*)d_in[21];
  const float* i2b    = (const float*)d_in[22];
  const float* redw   = (const float*)d_in[23];
  const float* redb   = (const float*)d_in[24];
  float* out = (float*)d_out;

  char* ws = (char*)d_ws;
  int*   idx_ws = (int*)(ws + WS_IDX);
  float* h1_ws  = (float*)(ws + WS_H1);
  float* pmax   = (float*)(ws + WS_PMAX);
  float* q_ws   = (float*)(ws + WS_Q);
  float* y_ws   = (float*)(ws + WS_Y);
  float* g2_ws  = (float*)(ws + WS_G2);
  float* basep  = (float*)(ws + WS_BASEP);
  float* pp     = (float*)(ws + WS_PP);   // reuses h1 region (dead after gc2)
  float* kv_ws  = (float*)(ws + WS_KV);   // reuses idx region (dead after gc2)
  float* vv_ws  = (float*)(ws + WS_VV);

  k_knn_gc1<<<4096, 256, 0, stream>>>(skel, g1wr, g1wl, g1b, idx_ws, h1_ws);
  k_gc2_max<<<512, 256, 0, stream>>>(h1_ws, idx_ws, g2wr, g2wl, g2b, pmax);
  k_proxy_kv<<<32, 384, 0, stream>>>(pmax, projw, projb, kv_ws);
  k_mv384<<<dim3(32, 12), 256, 0, stream>>>(kv_ws, aiw, 2*CC, aib, 2*CC, vv_ws); // vv
  k_mv384<<<dim3(32, 12), 256, 0, stream>>>(vv_ws, aow, 0,    aob, 0,    q_ws);  // q
  k_inc1_bn<<<512, 256, 0, stream>>>(q_ws, i1w, i1b, bng, bnb, bnm, bnv, y_ws);
  k_inc2<<<512, 256, 0, stream>>>(y_ws, i2w, i2b, g2_ws);
  k_basep<<<dim3(44, 6), 256, 0, stream>>>(g2_ws, q_ws, redw, pp);
  k_base_red<<<48, 256, 0, stream>>>(pp, basep);
  k_out<<<5376, 256, 0, stream>>>(basep, redb, redw, coarse, out);
}